// Round 11
// baseline (265.047 us; speedup 1.0000x reference)
//
#include <hip/hip_runtime.h>
#include <hip/hip_bf16.h>
#include <cstdint>
#include <cstddef>

// MHA: B=4, S=2048, D=512, H=8, DH=64. fp32 in/out.
// R20: flash-only change vs R19 -- T15 deferred-PV pipeline (m214v36,
//      +7-11% on attn). Flash's counter pair (MfmaUtil 33 / VALUBusy 36,
//      stable across 3 builds) = intra-wave serial chain QK->exp->PV with
//      only 2 waves/SIMD to fill the gaps. Defer PV by one tile: issue
//      PV(j-1) (independent of exp(j)) right after QK(j), so the matrix
//      pipe executes PV while the VALU runs exp. Same MFMA order per
//      accumulator -> bit-identical. +32 VGPR (carried pf/vf), no LDS or
//      barrier change. proj/split kernels = R19-exact.

typedef __bf16 bf16;
typedef __attribute__((ext_vector_type(8))) __bf16 bf16x8;
typedef __attribute__((ext_vector_type(4))) __bf16 bf16x4;
typedef __attribute__((ext_vector_type(4))) float floatx4;

#define MFMA16(a, b, c) __builtin_amdgcn_mfma_f32_16x16x32_bf16(a, b, c, 0, 0, 0)

#define GLD16(gp, lp)                                              \
  __builtin_amdgcn_global_load_lds(                                \
      (const __attribute__((address_space(1))) unsigned int*)(gp), \
      (__attribute__((address_space(3))) unsigned int*)(lp), 16, 0, 0)

#define PIPE_TOP()                                     \
  do {                                                 \
    asm volatile("s_waitcnt vmcnt(0)" ::: "memory");   \
    __builtin_amdgcn_s_barrier();                      \
    __builtin_amdgcn_sched_barrier(0);                 \
  } while (0)

#define LGKM_BARRIER()                                 \
  do {                                                 \
    asm volatile("s_waitcnt lgkmcnt(0)" ::: "memory"); \
    __builtin_amdgcn_sched_barrier(0);                 \
    __builtin_amdgcn_s_barrier();                      \
    __builtin_amdgcn_sched_barrier(0);                 \
  } while (0)

__device__ __forceinline__ void split2(float x, bf16& hi, bf16& lo) {
  hi = (bf16)x;
  lo = (bf16)(x - (float)hi);
}

// ---------------------------------------------------------------------------
// Split + transpose the 4 weight matrices: wt[w][n][k] = W_w[k][n] as hi/lo bf16
// ---------------------------------------------------------------------------
__global__ __launch_bounds__(256) void k_split_w(
    const float* __restrict__ Wq, const float* __restrict__ Wk,
    const float* __restrict__ Wv, const float* __restrict__ Wo,
    bf16* __restrict__ wt_hi, bf16* __restrict__ wt_lo) {
  __shared__ float tile[64][65];
  const int w = blockIdx.z;
  const float* W = (w == 0) ? Wq : (w == 1) ? Wk : (w == 2) ? Wv : Wo;
  const int kb = blockIdx.y * 64, nb = blockIdx.x * 64;
  const int tid = threadIdx.x;
  const int col = tid & 63, rbase = tid >> 6;
#pragma unroll
  for (int i = 0; i < 16; i++) {
    int row = rbase + i * 4;
    tile[row][col] = W[(size_t)(kb + row) * 512 + nb + col];
  }
  __syncthreads();
#pragma unroll
  for (int i = 0; i < 16; i++) {
    int nrow = rbase + i * 4;
    float v = tile[col][nrow];
    bf16 hi, lo;
    split2(v, hi, lo);
    size_t o = (size_t)w * 262144 + (size_t)(nb + nrow) * 512 + (kb + col);
    wt_hi[o] = hi;
    wt_lo[o] = lo;
  }
}

// ---------------------------------------------------------------------------
// Pre-split X (q,k,v inputs) into bf16 hi/lo. Elementwise, memory-bound.
// ---------------------------------------------------------------------------
__global__ __launch_bounds__(256) void k_split_x(
    const float* __restrict__ Xq, const float* __restrict__ Xk,
    const float* __restrict__ Xv,
    bf16* __restrict__ Xh, bf16* __restrict__ Xl) {
  const int total = 3 * 1048576;  // float4 granules (3 x 4M floats)
  for (int j = blockIdx.x * blockDim.x + threadIdx.x; j < total;
       j += gridDim.x * blockDim.x) {
    int w = j >> 20, off = j & 1048575;
    const float* X = (w == 0) ? Xq : (w == 1) ? Xk : Xv;
    floatx4 v = *(const floatx4*)(X + (size_t)off * 4);
    bf16x4 hv, lv;
#pragma unroll
    for (int r = 0; r < 4; r++) {
      bf16 h, l;
      split2(v[r], h, l);
      hv[r] = h; lv[r] = l;
    }
    *(bf16x4*)(Xh + (size_t)w * 4194304 + (size_t)off * 4) = hv;
    *(bf16x4*)(Xl + (size_t)w * 4194304 + (size_t)off * 4) = lv;
  }
}

// ---------------------------------------------------------------------------
// QKV projection, 128x128 C-tile, BK=32, pure-bf16 operands (pre-split X).
// Single-buffer GLD16 staging (32KB) + two-phase sync + setprio on MFMA
// cluster. (256,3) -> 3 blk/CU. grid 768, block 256. (R19-exact)
// ---------------------------------------------------------------------------
__global__ __launch_bounds__(256, 3) void k_proj_qkv(
    const bf16* __restrict__ Xh, const bf16* __restrict__ Xl,
    const bf16* __restrict__ wt_hi, const bf16* __restrict__ wt_lo,
    bf16* __restrict__ Q_hi, bf16* __restrict__ Q_lo,
    bf16* __restrict__ K, bf16* __restrict__ Vt) {
  const int P = blockIdx.x;
  const int c_all = P >> 5, within = P & 31;
  const int n_idx = within >> 3, i8 = within & 7;
  const int which = c_all >> 3;
  const int g = ((c_all & 7) << 3) | i8;  // m-group 0..63
  const int m0 = g * 128, n0 = n_idx * 128;

  const uint8_t* Ahb = (const uint8_t*)(Xh + (size_t)which * 4194304);
  const uint8_t* Alb = (const uint8_t*)(Xl + (size_t)which * 4194304);
  const uint8_t* Bhb = (const uint8_t*)(wt_hi + (size_t)which * 262144);
  const uint8_t* Blb = (const uint8_t*)(wt_lo + (size_t)which * 262144);
  const int tid = threadIdx.x, wave = tid >> 6, lane = tid & 63;
  const int l15 = lane & 15, l4 = lane >> 4;
  const int Am0 = (wave & 1) * 64, Bn0 = (wave >> 1) * 64;

  __shared__ bf16 sAh[128 * 32], sAl[128 * 32];  // 8 KB each
  __shared__ bf16 sBh[128 * 32], sBl[128 * 32];  // 8 KB each

  int aoff[2], boff[2], dstp[2];
#pragma unroll
  for (int p = 0; p < 2; p++) {
    int slot = p * 256 + tid;
    int row = slot >> 2, phys = slot & 3, lg = phys ^ (row & 3);
    aoff[p] = (m0 + row) * 1024 + lg * 16;
    boff[p] = (n0 + row) * 1024 + lg * 16;
    dstp[p] = slot * 16;
  }

  floatx4 acc[4][4];
#pragma unroll
  for (int i = 0; i < 4; i++)
#pragma unroll
    for (int j = 0; j < 4; j++) acc[i][j] = {0.f, 0.f, 0.f, 0.f};

  // prologue: issue stage(0)
#pragma unroll
  for (int p = 0; p < 2; p++) {
    GLD16(Ahb + aoff[p], (char*)sAh + dstp[p]);
    GLD16(Alb + aoff[p], (char*)sAl + dstp[p]);
    GLD16(Bhb + boff[p], (char*)sBh + dstp[p]);
    GLD16(Blb + boff[p], (char*)sBl + dstp[p]);
  }

  for (int kb = 0; kb < 512; kb += 32) {
    PIPE_TOP();  // stage(kb) landed

    bf16x8 ah[4], al[4], bhf[4], blf[4];
#pragma unroll
    for (int mt = 0; mt < 4; mt++) {
      int row = Am0 + mt * 16 + l15, r3 = row & 3;
      ah[mt] = *(const bf16x8*)((const char*)sAh + row * 64 + ((l4 ^ r3) * 16));
      al[mt] = *(const bf16x8*)((const char*)sAl + row * 64 + ((l4 ^ r3) * 16));
    }
#pragma unroll
    for (int nt = 0; nt < 4; nt++) {
      int row = Bn0 + nt * 16 + l15, r3 = row & 3;
      bhf[nt] = *(const bf16x8*)((const char*)sBh + row * 64 + ((l4 ^ r3) * 16));
      blf[nt] = *(const bf16x8*)((const char*)sBl + row * 64 + ((l4 ^ r3) * 16));
    }

    LGKM_BARRIER();  // all waves consumed -> safe to overwrite

    if (kb + 32 < 512) {
      const int nkb = kb + 32;
#pragma unroll
      for (int p = 0; p < 2; p++) {
        GLD16(Ahb + aoff[p] + nkb * 2, (char*)sAh + dstp[p]);
        GLD16(Alb + aoff[p] + nkb * 2, (char*)sAl + dstp[p]);
        GLD16(Bhb + boff[p] + nkb * 2, (char*)sBh + dstp[p]);
        GLD16(Blb + boff[p] + nkb * 2, (char*)sBl + dstp[p]);
      }
    }

    __builtin_amdgcn_s_setprio(1);
#pragma unroll
    for (int nt = 0; nt < 4; nt++) {
#pragma unroll
      for (int mt = 0; mt < 4; mt++) {
        acc[mt][nt] = MFMA16(ah[mt], bhf[nt], acc[mt][nt]);
        acc[mt][nt] = MFMA16(ah[mt], blf[nt], acc[mt][nt]);
        acc[mt][nt] = MFMA16(al[mt], bhf[nt], acc[mt][nt]);
      }
    }
    __builtin_amdgcn_s_setprio(0);
  }

  const float scale = (which == 0) ? 0.125f : (which == 1) ? 1.44269504f : 1.0f;
#pragma unroll
  for (int mt = 0; mt < 4; mt++) {
#pragma unroll
    for (int nt = 0; nt < 4; nt++) {
      int m_base = m0 + Am0 + mt * 16 + l4 * 4;  // 4 consecutive rows (s)
      int n = n0 + Bn0 + nt * 16 + l15;          // h*64+d
      int h = (n >> 6) & 7, d = n & 63;
      if (which == 2) {
        // slot-permuted packed V^T store: keys 16t+4q+r -> column 8q+4t+r
        int kbase = m_base & 2047, b = m_base >> 11;
        int a32 = kbase & ~31, v = (kbase >> 2) & 7;
        int sbase = a32 + 8 * (v & 3) + 4 * (v >> 2);
        bf16x4 pv;
#pragma unroll
        for (int r = 0; r < 4; r++) pv[r] = (bf16)acc[mt][nt][r];
        *(bf16x4*)&Vt[((size_t)(b * 8 + h) * 64 + d) * 2048 + sbase] = pv;
      } else {
#pragma unroll
        for (int r = 0; r < 4; r++) {
          int m = m_base + r;
          int b = m >> 11, s = m & 2047;
          float v = acc[mt][nt][r] * scale;
          size_t o = ((size_t)(b * 8 + h) * 2048 + s) * 64 + d;
          if (which == 0) {
            bf16 hi, lo;
            split2(v, hi, lo);
            Q_hi[o] = hi; Q_lo[o] = lo;
          } else {
            K[o] = (bf16)v;  // single bf16 K
          }
        }
      }
    }
  }
}

// ---------------------------------------------------------------------------
// Flash attention (R14 structure + T15 deferred-PV): grid 1024, block 256 =
// 4 waves; wave w owns keys [32w,32w+32). K/V dbuf (66.5KB) + counted-wait
// pipeline. Per iter: QK(j) -> PV(j-1) (independent of exp(j); executes in
// matrix pipe while exp(j) runs on VALU) -> exp(j) -> carry pf/vf. Final PV
// flushed after the loop. Same MFMA order per accumulator -> bit-identical.
// ---------------------------------------------------------------------------
__global__ __launch_bounds__(256, 2) void k_flash(
    const bf16* __restrict__ Q_hi, const bf16* __restrict__ Q_lo,
    const bf16* __restrict__ K, const bf16* __restrict__ Vt,
    bf16* __restrict__ O_hi, bf16* __restrict__ O_lo) {
  const int P = blockIdx.x;
  const int hi4 = P >> 8, rem = P & 255;
  const int qt = rem >> 3;
  const int bh = hi4 * 8 + (rem & 7);
  const int b = bh >> 3, h = bh & 7;
  const int tid = threadIdx.x, wave = tid >> 6, lane = tid & 63;
  const int l15 = lane & 15, l4 = lane >> 4;
  const int q0 = qt * 64;

  // buf c: sK @ c*32768 (16KB) | sV @ c*32768+16384 (16KB); lbuf @ 65536 (1KB)
  __shared__ char smem[2 * 32768 + 1024];
  float* lbuf = (float*)(smem + 65536);

  const uint8_t* Kb = (const uint8_t*)K + (size_t)bh * 2048 * 128;
  const uint8_t* Vb = (const uint8_t*)Vt + (size_t)bh * 64 * 4096;
  int koff[4], voff[4], dst[4];
#pragma unroll
  for (int p = 0; p < 4; p++) {
    int slot = p * 256 + tid;
    {
      int row = slot >> 3, phys = slot & 7, lg = phys ^ (row & 7);
      koff[p] = row * 128 + lg * 16;
    }
    {
      int row = slot >> 4, phys = slot & 15, lg = phys ^ (row & 15);
      voff[p] = row * 4096 + lg * 16;
    }
    dst[p] = slot * 16;
  }

  // prologue: issue stage j0=0 into buf 0 (in flight under Q loads)
#pragma unroll
  for (int p = 0; p < 4; p++) {
    GLD16(Kb + koff[p], smem + dst[p]);
    GLD16(Vb + voff[p], smem + 16384 + dst[p]);
  }

  // Q fragments (B operand): lane holds Q[q=l15][dh=l4*8+j]
  bf16x8 qh[4][2], ql[4][2];
#pragma unroll
  for (int nt = 0; nt < 4; nt++) {
    const bf16* ph = Q_hi + ((size_t)bh * 2048 + q0 + nt * 16 + l15) * 64 + l4 * 8;
    const bf16* pl = Q_lo + ((size_t)bh * 2048 + q0 + nt * 16 + l15) * 64 + l4 * 8;
    qh[nt][0] = *(const bf16x8*)ph;
    qh[nt][1] = *(const bf16x8*)(ph + 32);
    ql[nt][0] = *(const bf16x8*)pl;
    ql[nt][1] = *(const bf16x8*)(pl + 32);
  }

  float lp[4] = {0.f, 0.f, 0.f, 0.f};  // l partial per q-tile (q = nt*16+l15)
  floatx4 oacc[4][4];
#pragma unroll
  for (int i = 0; i < 4; i++)
#pragma unroll
    for (int j = 0; j < 4; j++) oacc[i][j] = {0.f, 0.f, 0.f, 0.f};

  bf16x8 pfP[4], vfP[4];  // previous tile's P fragments + V fragments

  int cur = 0;
#pragma unroll 2
  for (int j0 = 0; j0 < 2048; j0 += 128) {
    PIPE_TOP();  // stage(j0) landed (issued last iter); all waves synced

    const char* sK = smem + cur * 32768;
    const char* sV = sK + 16384;

    // K/V fragments -> regs (8 x ds_read_b128), before next-stage issue
    bf16x8 kf[2][2];  // [ks][kt]
#pragma unroll
    for (int kt = 0; kt < 2; kt++) {
      int row = wave * 32 + kt * 16 + l15, r7 = row & 7;
#pragma unroll
      for (int ks = 0; ks < 2; ks++)
        kf[ks][kt] =
            *(const bf16x8*)(sK + row * 128 + (((ks * 4 + l4) ^ r7) * 16));
    }
    bf16x8 vf[4];
#pragma unroll
    for (int nt = 0; nt < 4; nt++) {
      int row = nt * 16 + l15;
      vf[nt] =
          *(const bf16x8*)(sV + row * 256 + (((wave * 4 + l4) ^ l15) * 16));
    }

    // issue next key-tile into the other buffer; in flight under compute
    if (j0 + 128 < 2048) {
      char* nb = smem + (cur ^ 1) * 32768;
      const size_t nj = (size_t)(j0 + 128);
#pragma unroll
      for (int p = 0; p < 4; p++) {
        GLD16(Kb + nj * 128 + koff[p], nb + dst[p]);
        GLD16(Vb + nj * 2 + voff[p], nb + 16384 + dst[p]);
      }
    }

    // S^T = K Q^T - 24: sc[kt][nt] C-tile: row=key(16), col=q (l15)
    floatx4 sc[2][4];
#pragma unroll
    for (int kt = 0; kt < 2; kt++)
#pragma unroll
      for (int nt = 0; nt < 4; nt++)
        sc[kt][nt] = {-24.f, -24.f, -24.f, -24.f};
#pragma unroll
    for (int ks = 0; ks < 2; ks++) {
#pragma unroll
      for (int nt = 0; nt < 4; nt++) {
        sc[0][nt] = MFMA16(kf[ks][0], qh[nt][ks], sc[0][nt]);
        sc[0][nt] = MFMA16(kf[ks][0], ql[nt][ks], sc[0][nt]);
        sc[1][nt] = MFMA16(kf[ks][1], qh[nt][ks], sc[1][nt]);
        sc[1][nt] = MFMA16(kf[ks][1], ql[nt][ks], sc[1][nt]);
      }
    }

    // Deferred PV(j-1): independent of exp(j); matrix pipe executes these
    // while the VALU below computes exp(j).
    if (j0) {
#pragma unroll
      for (int nt = 0; nt < 4; nt++) {
#pragma unroll
        for (int mq = 0; mq < 4; mq++)
          oacc[mq][nt] = MFMA16(pfP[mq], vfP[nt], oacc[mq][nt]);
      }
    }

    // p = exp2(s); pf[nt] directly the PV A-operand (slot = quad*8 + 4*kt + r)
    bf16x8 pf[4];
#pragma unroll
    for (int nt = 0; nt < 4; nt++) {
#pragma unroll
      for (int r = 0; r < 4; r++) {
        float p0 = __builtin_amdgcn_exp2f(sc[0][nt][r]);
        float p1 = __builtin_amdgcn_exp2f(sc[1][nt][r]);
        lp[nt] += p0 + p1;
        pf[nt][r] = (bf16)p0;
        pf[nt][4 + r] = (bf16)p1;
      }
    }

    // carry this tile's P and V fragments to the next iteration
#pragma unroll
    for (int nt = 0; nt < 4; nt++) {
      pfP[nt] = pf[nt];
      vfP[nt] = vf[nt];
    }
    cur ^= 1;
  }

  // flush the last tile's PV
#pragma unroll
  for (int nt = 0; nt < 4; nt++) {
#pragma unroll
    for (int mq = 0; mq < 4; mq++)
      oacc[mq][nt] = MFMA16(pfP[mq], vfP[nt], oacc[mq][nt]);
  }

  // ---- epilogue: l reduce + two-phase cross-wave O reduction (24KB alias) ----
#pragma unroll
  for (int nt = 0; nt < 4; nt++) {
    lp[nt] += __shfl_xor(lp[nt], 16, 64);
    lp[nt] += __shfl_xor(lp[nt], 32, 64);
  }
  __syncthreads();  // all waves done with K/V buffers before aliasing
  if (l4 == 0) {
#pragma unroll
    for (int nt = 0; nt < 4; nt++) lbuf[wave * 64 + nt * 16 + l15] = lp[nt];
  }
  floatx4* red = (floatx4*)smem;  // 3 waves x 8 x 64 = 1536 floatx4 = 24KB
#pragma unroll
  for (int phase = 0; phase < 2; phase++) {
    if (wave >= 1) {
#pragma unroll
      for (int i = 0; i < 8; i++) {
        int mq = phase * 2 + (i >> 2);
        red[(wave - 1) * 512 + i * 64 + lane] = oacc[mq][i & 3];
      }
    }
    __syncthreads();
    if (wave == 0) {
#pragma unroll
      for (int i = 0; i < 8; i++) {
        int mq = phase * 2 + (i >> 2);
        oacc[mq][i & 3] += red[i * 64 + lane] + red[512 + i * 64 + lane] +
                           red[1024 + i * 64 + lane];
      }
    }
    __syncthreads();
  }
  if (wave == 0) {
    float lt[4];
#pragma unroll
    for (int nt = 0; nt < 4; nt++)
      lt[nt] = lbuf[nt * 16 + l15] + lbuf[64 + nt * 16 + l15] +
               lbuf[128 + nt * 16 + l15] + lbuf[192 + nt * 16 + l15];
    float rl[4][4];
#pragma unroll
    for (int mq = 0; mq < 4; mq++)
#pragma unroll
      for (int r = 0; r < 4; r++)
        rl[mq][r] = 1.0f / __shfl(lt[mq], (lane & 48) | (l4 * 4 + r), 64);
#pragma unroll
    for (int mq = 0; mq < 4; mq++) {
#pragma unroll
      for (int nt = 0; nt < 4; nt++) {
#pragma unroll
        for (int r = 0; r < 4; r++) {
          float v = oacc[mq][nt][r] * rl[mq][r];
          int gs = q0 + mq * 16 + l4 * 4 + r;
          int gd = h * 64 + nt * 16 + l15;
          size_t o = ((size_t)b * 2048 + gs) * 512 + gd;
          bf16 hi, lo;
          split2(v, hi, lo);
          O_hi[o] = hi;
          O_lo[o] = lo;
        }
      }
    }
  }
}

// ---------------------------------------------------------------------------
// Output projection, 64x128 C-tile, BK=32, single-buffer (24KB) two-phase
// sync + setprio. grid 512, m-major -> 2 blocks/CU. (R19-exact)
// ---------------------------------------------------------------------------
__global__ __launch_bounds__(256, 2) void k_proj_out(
    const bf16* __restrict__ O_hi, const bf16* __restrict__ O_lo,
    const bf16* __restrict__ wt_hi, const bf16* __restrict__ wt_lo,
    float* __restrict__ out) {
  const int P = blockIdx.x;
  const int g = P & 127, n_idx = P >> 7;
  const int m0 = g * 64, n0 = n_idx * 128;

  const uint8_t* Ahb = (const uint8_t*)O_hi;
  const uint8_t* Alb = (const uint8_t*)O_lo;
  const uint8_t* Bhb = (const uint8_t*)(wt_hi + (size_t)3 * 262144);
  const uint8_t* Blb = (const uint8_t*)(wt_lo + (size_t)3 * 262144);
  const int tid = threadIdx.x, wave = tid >> 6, lane = tid & 63;
  const int l15 = lane & 15, l4 = lane >> 4;
  const int Am0 = (wave & 1) * 32, Bn0 = (wave >> 1) * 64;

  __shared__ bf16 sAh[64 * 32], sAl[64 * 32];    // 4 KB each
  __shared__ bf16 sBh[128 * 32], sBl[128 * 32];  // 8 KB each

  int aoff, adst;
  {
    int slot = tid;
    int row = slot >> 2, phys = slot & 3, lg = phys ^ (row & 3);
    aoff = (m0 + row) * 1024 + lg * 16;
    adst = slot * 16;
  }
  int boff[2], bdst[2];
#pragma unroll
  for (int p = 0; p < 2; p++) {
    int slot = p * 256 + tid;
    int row = slot >> 2, phys = slot & 3, lg = phys ^ (row & 3);
    boff[p] = (n0 + row) * 1024 + lg * 16;
    bdst[p] = slot * 16;
  }

  floatx4 acc[2][4];
#pragma unroll
  for (int i = 0; i < 2; i++)
#pragma unroll
    for (int j = 0; j < 4; j++) acc[i][j] = {0.f, 0.f, 0.f, 0.f};

  // prologue: issue stage(0)
  GLD16(Ahb + aoff, (char*)sAh + adst);
  GLD16(Alb + aoff, (char*)sAl + adst);
#pragma unroll
  for (int p = 0; p < 2; p++) {
    GLD16(Bhb + boff[p], (char*)sBh + bdst[p]);
    GLD16(Blb + boff[p], (char*)sBl + bdst[p]);
  }

  for (int kb = 0; kb < 512; kb += 32) {
    PIPE_TOP();

    bf16x8 ah[2], al[2], bhf[4], blf[4];
#pragma unroll
    for (int mt = 0; mt < 2; mt++) {
      int row = Am0 + mt * 16 + l15, r3 = row & 3;
      ah[mt] = *(const bf16x8*)((const char*)sAh + row * 64 + ((l4 ^ r3) * 16));
      al[mt] = *(const bf16x8*)((const char*)sAl + row * 64 + ((l4 ^ r3) * 16));
    }
#pragma unroll
    for (int nt = 0; nt < 4; nt++) {
      int row = Bn0 + nt * 16 + l15, r3 = row & 3;
      bhf[nt] = *(const bf16x8*)((const char*)sBh + row * 64 + ((l4 ^ r3) * 16));
      blf[nt] = *(const bf16x8*)((const char*)sBl + row * 64 + ((l4 ^ r3) * 16));
    }

    LGKM_BARRIER();

    if (kb + 32 < 512) {
      const int nkb = kb + 32;
      GLD16(Ahb + aoff + nkb * 2, (char*)sAh + adst);
      GLD16(Alb + aoff + nkb * 2, (char*)sAl + adst);
#pragma unroll
      for (int p = 0; p < 2; p++) {
        GLD16(Bhb + boff[p] + nkb * 2, (char*)sBh + bdst[p]);
        GLD16(Blb + boff[p] + nkb * 2, (char*)sBl + bdst[p]);
      }
    }

    __builtin_amdgcn_s_setprio(1);
#pragma unroll
    for (int nt = 0; nt < 4; nt++) {
#pragma unroll
      for (int mt = 0; mt < 2; mt++) {
        acc[mt][nt] = MFMA16(ah[mt], bhf[nt], acc[mt][nt]);
        acc[mt][nt] = MFMA16(ah[mt], blf[nt], acc[mt][nt]);
        acc[mt][nt] = MFMA16(al[mt], bhf[nt], acc[mt][nt]);
      }
    }
    __builtin_amdgcn_s_setprio(0);
  }
#pragma unroll
  for (int mt = 0; mt < 2; mt++) {
#pragma unroll
    for (int nt = 0; nt < 4; nt++) {
#pragma unroll
      for (int r = 0; r < 4; r++) {
        int m = m0 + Am0 + mt * 16 + l4 * 4 + r;
        int n = n0 + Bn0 + nt * 16 + l15;
        out[(size_t)m * 512 + n] = acc[mt][nt][r];
      }
    }
  }
}

// ---------------------------------------------------------------------------
extern "C" void kernel_launch(void* const* d_in, const int* in_sizes, int n_in,
                              void* d_out, int out_size, void* d_ws, size_t ws_size,
                              hipStream_t stream) {
  (void)in_sizes; (void)n_in; (void)out_size; (void)ws_size;
  const float* Xq = (const float*)d_in[0];
  const float* Xk = (const float*)d_in[1];
  const float* Xv = (const float*)d_in[2];
  const float* Wq = (const float*)d_in[3];
  const float* Wk = (const float*)d_in[4];
  const float* Wv = (const float*)d_in[5];
  const float* Wo = (const float*)d_in[6];
  float* out = (float*)d_out;

  char* ws = (char*)d_ws;
  size_t off = 0;
  auto alloc = [&](size_t n) {
    void* p = ws + off;
    off += (n + 255) & ~(size_t)255;
    return p;
  };
  const size_t NW = 4 * 262144;
  const size_t NE = 4194304;       // 4*2048*512
  const size_t NX = 3 * 4194304;   // all three X inputs
  bf16* wt_hi = (bf16*)alloc(NW * 2);
  bf16* wt_lo = (bf16*)alloc(NW * 2);
  bf16* Qh = (bf16*)alloc(NE * 2);
  bf16* Ql = (bf16*)alloc(NE * 2);
  bf16* Kk = (bf16*)alloc(NE * 2);
  bf16* Vt = (bf16*)alloc(NE * 2);
  // Xh/Xl alias Oh/Ol: Xh,Xl dead before flash writes Oh,Ol.
  char* shared_region = (char*)alloc(2 * NX * 2);
  bf16* Xh = (bf16*)shared_region;
  bf16* Xl = Xh + NX;
  bf16* Oh = (bf16*)shared_region;
  bf16* Ol = Oh + NE;

  k_split_w<<<dim3(8, 8, 4), dim3(256), 0, stream>>>(Wq, Wk, Wv, Wo, wt_hi, wt_lo);
  k_split_x<<<dim3(2048), dim3(256), 0, stream>>>(Xq, Xk, Xv, Xh, Xl);
  k_proj_qkv<<<dim3(768), dim3(256), 0, stream>>>(Xh, Xl, wt_hi, wt_lo,
                                                  Qh, Ql, Kk, Vt);
  k_flash<<<dim3(1024), dim3(256), 0, stream>>>(Qh, Ql, Kk, Vt, Oh, Ol);
  k_proj_out<<<dim3(512), dim3(256), 0, stream>>>(Oh, Ol, wt_hi, wt_lo, out);
}

// Round 12
// 221.846 us; speedup vs baseline: 1.1947x; 1.1947x over previous
//
#include <hip/hip_runtime.h>
#include <hip/hip_bf16.h>
#include <cstdint>
#include <cstddef>

// MHA: B=4, S=2048, D=512, H=8, DH=64. fp32 in/out.
// R21: R20's T15 deferred-PV retry with the spill bug fixed. R20's 107us
//      regression was NOT the schedule: WRITE_SIZE 16->87MB = scratch spill
//      caused by '#pragma unroll 2' keeping two iteration bodies' live sets
//      (kf/vf/sc/pf ~64 VGPR) overlapping the carried pfP/vfP. Plain loop:
//      ~152 VGPR < 256 cap -> no spill. Deferred PV(j-1) issues after QK(j)
//      so the matrix pipe executes it while exp(j) runs on the VALU (the
//      MfmaUtil33/VALUBusy36 serial-chain gap). Same MFMA order per
//      accumulator -> bit-identical. proj/split kernels = R19-exact.

typedef __bf16 bf16;
typedef __attribute__((ext_vector_type(8))) __bf16 bf16x8;
typedef __attribute__((ext_vector_type(4))) __bf16 bf16x4;
typedef __attribute__((ext_vector_type(4))) float floatx4;

#define MFMA16(a, b, c) __builtin_amdgcn_mfma_f32_16x16x32_bf16(a, b, c, 0, 0, 0)

#define GLD16(gp, lp)                                              \
  __builtin_amdgcn_global_load_lds(                                \
      (const __attribute__((address_space(1))) unsigned int*)(gp), \
      (__attribute__((address_space(3))) unsigned int*)(lp), 16, 0, 0)

#define PIPE_TOP()                                     \
  do {                                                 \
    asm volatile("s_waitcnt vmcnt(0)" ::: "memory");   \
    __builtin_amdgcn_s_barrier();                      \
    __builtin_amdgcn_sched_barrier(0);                 \
  } while (0)

#define LGKM_BARRIER()                                 \
  do {                                                 \
    asm volatile("s_waitcnt lgkmcnt(0)" ::: "memory"); \
    __builtin_amdgcn_sched_barrier(0);                 \
    __builtin_amdgcn_s_barrier();                      \
    __builtin_amdgcn_sched_barrier(0);                 \
  } while (0)

__device__ __forceinline__ void split2(float x, bf16& hi, bf16& lo) {
  hi = (bf16)x;
  lo = (bf16)(x - (float)hi);
}

// ---------------------------------------------------------------------------
// Split + transpose the 4 weight matrices: wt[w][n][k] = W_w[k][n] as hi/lo bf16
// ---------------------------------------------------------------------------
__global__ __launch_bounds__(256) void k_split_w(
    const float* __restrict__ Wq, const float* __restrict__ Wk,
    const float* __restrict__ Wv, const float* __restrict__ Wo,
    bf16* __restrict__ wt_hi, bf16* __restrict__ wt_lo) {
  __shared__ float tile[64][65];
  const int w = blockIdx.z;
  const float* W = (w == 0) ? Wq : (w == 1) ? Wk : (w == 2) ? Wv : Wo;
  const int kb = blockIdx.y * 64, nb = blockIdx.x * 64;
  const int tid = threadIdx.x;
  const int col = tid & 63, rbase = tid >> 6;
#pragma unroll
  for (int i = 0; i < 16; i++) {
    int row = rbase + i * 4;
    tile[row][col] = W[(size_t)(kb + row) * 512 + nb + col];
  }
  __syncthreads();
#pragma unroll
  for (int i = 0; i < 16; i++) {
    int nrow = rbase + i * 4;
    float v = tile[col][nrow];
    bf16 hi, lo;
    split2(v, hi, lo);
    size_t o = (size_t)w * 262144 + (size_t)(nb + nrow) * 512 + (kb + col);
    wt_hi[o] = hi;
    wt_lo[o] = lo;
  }
}

// ---------------------------------------------------------------------------
// Pre-split X (q,k,v inputs) into bf16 hi/lo. Elementwise, memory-bound.
// ---------------------------------------------------------------------------
__global__ __launch_bounds__(256) void k_split_x(
    const float* __restrict__ Xq, const float* __restrict__ Xk,
    const float* __restrict__ Xv,
    bf16* __restrict__ Xh, bf16* __restrict__ Xl) {
  const int total = 3 * 1048576;  // float4 granules (3 x 4M floats)
  for (int j = blockIdx.x * blockDim.x + threadIdx.x; j < total;
       j += gridDim.x * blockDim.x) {
    int w = j >> 20, off = j & 1048575;
    const float* X = (w == 0) ? Xq : (w == 1) ? Xk : Xv;
    floatx4 v = *(const floatx4*)(X + (size_t)off * 4);
    bf16x4 hv, lv;
#pragma unroll
    for (int r = 0; r < 4; r++) {
      bf16 h, l;
      split2(v[r], h, l);
      hv[r] = h; lv[r] = l;
    }
    *(bf16x4*)(Xh + (size_t)w * 4194304 + (size_t)off * 4) = hv;
    *(bf16x4*)(Xl + (size_t)w * 4194304 + (size_t)off * 4) = lv;
  }
}

// ---------------------------------------------------------------------------
// QKV projection, 128x128 C-tile, BK=32, pure-bf16 operands (pre-split X).
// Single-buffer GLD16 staging (32KB) + two-phase sync + setprio on MFMA
// cluster. (256,3) -> 3 blk/CU. grid 768, block 256. (R19-exact)
// ---------------------------------------------------------------------------
__global__ __launch_bounds__(256, 3) void k_proj_qkv(
    const bf16* __restrict__ Xh, const bf16* __restrict__ Xl,
    const bf16* __restrict__ wt_hi, const bf16* __restrict__ wt_lo,
    bf16* __restrict__ Q_hi, bf16* __restrict__ Q_lo,
    bf16* __restrict__ K, bf16* __restrict__ Vt) {
  const int P = blockIdx.x;
  const int c_all = P >> 5, within = P & 31;
  const int n_idx = within >> 3, i8 = within & 7;
  const int which = c_all >> 3;
  const int g = ((c_all & 7) << 3) | i8;  // m-group 0..63
  const int m0 = g * 128, n0 = n_idx * 128;

  const uint8_t* Ahb = (const uint8_t*)(Xh + (size_t)which * 4194304);
  const uint8_t* Alb = (const uint8_t*)(Xl + (size_t)which * 4194304);
  const uint8_t* Bhb = (const uint8_t*)(wt_hi + (size_t)which * 262144);
  const uint8_t* Blb = (const uint8_t*)(wt_lo + (size_t)which * 262144);
  const int tid = threadIdx.x, wave = tid >> 6, lane = tid & 63;
  const int l15 = lane & 15, l4 = lane >> 4;
  const int Am0 = (wave & 1) * 64, Bn0 = (wave >> 1) * 64;

  __shared__ bf16 sAh[128 * 32], sAl[128 * 32];  // 8 KB each
  __shared__ bf16 sBh[128 * 32], sBl[128 * 32];  // 8 KB each

  int aoff[2], boff[2], dstp[2];
#pragma unroll
  for (int p = 0; p < 2; p++) {
    int slot = p * 256 + tid;
    int row = slot >> 2, phys = slot & 3, lg = phys ^ (row & 3);
    aoff[p] = (m0 + row) * 1024 + lg * 16;
    boff[p] = (n0 + row) * 1024 + lg * 16;
    dstp[p] = slot * 16;
  }

  floatx4 acc[4][4];
#pragma unroll
  for (int i = 0; i < 4; i++)
#pragma unroll
    for (int j = 0; j < 4; j++) acc[i][j] = {0.f, 0.f, 0.f, 0.f};

  // prologue: issue stage(0)
#pragma unroll
  for (int p = 0; p < 2; p++) {
    GLD16(Ahb + aoff[p], (char*)sAh + dstp[p]);
    GLD16(Alb + aoff[p], (char*)sAl + dstp[p]);
    GLD16(Bhb + boff[p], (char*)sBh + dstp[p]);
    GLD16(Blb + boff[p], (char*)sBl + dstp[p]);
  }

  for (int kb = 0; kb < 512; kb += 32) {
    PIPE_TOP();  // stage(kb) landed

    bf16x8 ah[4], al[4], bhf[4], blf[4];
#pragma unroll
    for (int mt = 0; mt < 4; mt++) {
      int row = Am0 + mt * 16 + l15, r3 = row & 3;
      ah[mt] = *(const bf16x8*)((const char*)sAh + row * 64 + ((l4 ^ r3) * 16));
      al[mt] = *(const bf16x8*)((const char*)sAl + row * 64 + ((l4 ^ r3) * 16));
    }
#pragma unroll
    for (int nt = 0; nt < 4; nt++) {
      int row = Bn0 + nt * 16 + l15, r3 = row & 3;
      bhf[nt] = *(const bf16x8*)((const char*)sBh + row * 64 + ((l4 ^ r3) * 16));
      blf[nt] = *(const bf16x8*)((const char*)sBl + row * 64 + ((l4 ^ r3) * 16));
    }

    LGKM_BARRIER();  // all waves consumed -> safe to overwrite

    if (kb + 32 < 512) {
      const int nkb = kb + 32;
#pragma unroll
      for (int p = 0; p < 2; p++) {
        GLD16(Ahb + aoff[p] + nkb * 2, (char*)sAh + dstp[p]);
        GLD16(Alb + aoff[p] + nkb * 2, (char*)sAl + dstp[p]);
        GLD16(Bhb + boff[p] + nkb * 2, (char*)sBh + dstp[p]);
        GLD16(Blb + boff[p] + nkb * 2, (char*)sBl + dstp[p]);
      }
    }

    __builtin_amdgcn_s_setprio(1);
#pragma unroll
    for (int nt = 0; nt < 4; nt++) {
#pragma unroll
      for (int mt = 0; mt < 4; mt++) {
        acc[mt][nt] = MFMA16(ah[mt], bhf[nt], acc[mt][nt]);
        acc[mt][nt] = MFMA16(ah[mt], blf[nt], acc[mt][nt]);
        acc[mt][nt] = MFMA16(al[mt], bhf[nt], acc[mt][nt]);
      }
    }
    __builtin_amdgcn_s_setprio(0);
  }

  const float scale = (which == 0) ? 0.125f : (which == 1) ? 1.44269504f : 1.0f;
#pragma unroll
  for (int mt = 0; mt < 4; mt++) {
#pragma unroll
    for (int nt = 0; nt < 4; nt++) {
      int m_base = m0 + Am0 + mt * 16 + l4 * 4;  // 4 consecutive rows (s)
      int n = n0 + Bn0 + nt * 16 + l15;          // h*64+d
      int h = (n >> 6) & 7, d = n & 63;
      if (which == 2) {
        // slot-permuted packed V^T store: keys 16t+4q+r -> column 8q+4t+r
        int kbase = m_base & 2047, b = m_base >> 11;
        int a32 = kbase & ~31, v = (kbase >> 2) & 7;
        int sbase = a32 + 8 * (v & 3) + 4 * (v >> 2);
        bf16x4 pv;
#pragma unroll
        for (int r = 0; r < 4; r++) pv[r] = (bf16)acc[mt][nt][r];
        *(bf16x4*)&Vt[((size_t)(b * 8 + h) * 64 + d) * 2048 + sbase] = pv;
      } else {
#pragma unroll
        for (int r = 0; r < 4; r++) {
          int m = m_base + r;
          int b = m >> 11, s = m & 2047;
          float v = acc[mt][nt][r] * scale;
          size_t o = ((size_t)(b * 8 + h) * 2048 + s) * 64 + d;
          if (which == 0) {
            bf16 hi, lo;
            split2(v, hi, lo);
            Q_hi[o] = hi; Q_lo[o] = lo;
          } else {
            K[o] = (bf16)v;  // single bf16 K
          }
        }
      }
    }
  }
}

// ---------------------------------------------------------------------------
// Flash attention (R14 structure + T15 deferred-PV, NO unroll): grid 1024,
// block 256 = 4 waves; wave w owns keys [32w,32w+32). K/V dbuf (66.5KB) +
// counted-wait pipeline. Per iter: QK(j) -> PV(j-1) -> exp(j) -> carry.
// Final PV flushed after the loop. Same MFMA order per accumulator ->
// bit-identical.
// ---------------------------------------------------------------------------
__global__ __launch_bounds__(256, 2) void k_flash(
    const bf16* __restrict__ Q_hi, const bf16* __restrict__ Q_lo,
    const bf16* __restrict__ K, const bf16* __restrict__ Vt,
    bf16* __restrict__ O_hi, bf16* __restrict__ O_lo) {
  const int P = blockIdx.x;
  const int hi4 = P >> 8, rem = P & 255;
  const int qt = rem >> 3;
  const int bh = hi4 * 8 + (rem & 7);
  const int b = bh >> 3, h = bh & 7;
  const int tid = threadIdx.x, wave = tid >> 6, lane = tid & 63;
  const int l15 = lane & 15, l4 = lane >> 4;
  const int q0 = qt * 64;

  // buf c: sK @ c*32768 (16KB) | sV @ c*32768+16384 (16KB); lbuf @ 65536 (1KB)
  __shared__ char smem[2 * 32768 + 1024];
  float* lbuf = (float*)(smem + 65536);

  const uint8_t* Kb = (const uint8_t*)K + (size_t)bh * 2048 * 128;
  const uint8_t* Vb = (const uint8_t*)Vt + (size_t)bh * 64 * 4096;
  int koff[4], voff[4], dst[4];
#pragma unroll
  for (int p = 0; p < 4; p++) {
    int slot = p * 256 + tid;
    {
      int row = slot >> 3, phys = slot & 7, lg = phys ^ (row & 7);
      koff[p] = row * 128 + lg * 16;
    }
    {
      int row = slot >> 4, phys = slot & 15, lg = phys ^ (row & 15);
      voff[p] = row * 4096 + lg * 16;
    }
    dst[p] = slot * 16;
  }

  // prologue: issue stage j0=0 into buf 0 (in flight under Q loads)
#pragma unroll
  for (int p = 0; p < 4; p++) {
    GLD16(Kb + koff[p], smem + dst[p]);
    GLD16(Vb + voff[p], smem + 16384 + dst[p]);
  }

  // Q fragments (B operand): lane holds Q[q=l15][dh=l4*8+j]
  bf16x8 qh[4][2], ql[4][2];
#pragma unroll
  for (int nt = 0; nt < 4; nt++) {
    const bf16* ph = Q_hi + ((size_t)bh * 2048 + q0 + nt * 16 + l15) * 64 + l4 * 8;
    const bf16* pl = Q_lo + ((size_t)bh * 2048 + q0 + nt * 16 + l15) * 64 + l4 * 8;
    qh[nt][0] = *(const bf16x8*)ph;
    qh[nt][1] = *(const bf16x8*)(ph + 32);
    ql[nt][0] = *(const bf16x8*)pl;
    ql[nt][1] = *(const bf16x8*)(pl + 32);
  }

  float lp[4] = {0.f, 0.f, 0.f, 0.f};  // l partial per q-tile (q = nt*16+l15)
  floatx4 oacc[4][4];
#pragma unroll
  for (int i = 0; i < 4; i++)
#pragma unroll
    for (int j = 0; j < 4; j++) oacc[i][j] = {0.f, 0.f, 0.f, 0.f};

  bf16x8 pfP[4], vfP[4];  // previous tile's P fragments + V fragments

  int cur = 0;
  for (int j0 = 0; j0 < 2048; j0 += 128) {
    PIPE_TOP();  // stage(j0) landed (issued last iter); all waves synced

    const char* sK = smem + cur * 32768;
    const char* sV = sK + 16384;

    // K/V fragments -> regs (8 x ds_read_b128), before next-stage issue
    bf16x8 kf[2][2];  // [ks][kt]
#pragma unroll
    for (int kt = 0; kt < 2; kt++) {
      int row = wave * 32 + kt * 16 + l15, r7 = row & 7;
#pragma unroll
      for (int ks = 0; ks < 2; ks++)
        kf[ks][kt] =
            *(const bf16x8*)(sK + row * 128 + (((ks * 4 + l4) ^ r7) * 16));
    }
    bf16x8 vf[4];
#pragma unroll
    for (int nt = 0; nt < 4; nt++) {
      int row = nt * 16 + l15;
      vf[nt] =
          *(const bf16x8*)(sV + row * 256 + (((wave * 4 + l4) ^ l15) * 16));
    }

    // issue next key-tile into the other buffer; in flight under compute
    if (j0 + 128 < 2048) {
      char* nb = smem + (cur ^ 1) * 32768;
      const size_t nj = (size_t)(j0 + 128);
#pragma unroll
      for (int p = 0; p < 4; p++) {
        GLD16(Kb + nj * 128 + koff[p], nb + dst[p]);
        GLD16(Vb + nj * 2 + voff[p], nb + 16384 + dst[p]);
      }
    }

    // S^T = K Q^T - 24: sc[kt][nt] C-tile: row=key(16), col=q (l15)
    floatx4 sc[2][4];
#pragma unroll
    for (int kt = 0; kt < 2; kt++)
#pragma unroll
      for (int nt = 0; nt < 4; nt++)
        sc[kt][nt] = {-24.f, -24.f, -24.f, -24.f};
#pragma unroll
    for (int ks = 0; ks < 2; ks++) {
#pragma unroll
      for (int nt = 0; nt < 4; nt++) {
        sc[0][nt] = MFMA16(kf[ks][0], qh[nt][ks], sc[0][nt]);
        sc[0][nt] = MFMA16(kf[ks][0], ql[nt][ks], sc[0][nt]);
        sc[1][nt] = MFMA16(kf[ks][1], qh[nt][ks], sc[1][nt]);
        sc[1][nt] = MFMA16(kf[ks][1], ql[nt][ks], sc[1][nt]);
      }
    }

    // Deferred PV(j-1): independent of exp(j); matrix pipe executes these
    // while the VALU below computes exp(j).
    if (j0) {
#pragma unroll
      for (int nt = 0; nt < 4; nt++) {
#pragma unroll
        for (int mq = 0; mq < 4; mq++)
          oacc[mq][nt] = MFMA16(pfP[mq], vfP[nt], oacc[mq][nt]);
      }
    }

    // p = exp2(s); pf directly the PV A-operand (slot = quad*8 + 4*kt + r)
#pragma unroll
    for (int nt = 0; nt < 4; nt++) {
      bf16x8 pf;
#pragma unroll
      for (int r = 0; r < 4; r++) {
        float p0 = __builtin_amdgcn_exp2f(sc[0][nt][r]);
        float p1 = __builtin_amdgcn_exp2f(sc[1][nt][r]);
        lp[nt] += p0 + p1;
        pf[r] = (bf16)p0;
        pf[4 + r] = (bf16)p1;
      }
      pfP[nt] = pf;
      vfP[nt] = vf[nt];
    }
    cur ^= 1;
  }

  // flush the last tile's PV
#pragma unroll
  for (int nt = 0; nt < 4; nt++) {
#pragma unroll
    for (int mq = 0; mq < 4; mq++)
      oacc[mq][nt] = MFMA16(pfP[mq], vfP[nt], oacc[mq][nt]);
  }

  // ---- epilogue: l reduce + two-phase cross-wave O reduction (24KB alias) ----
#pragma unroll
  for (int nt = 0; nt < 4; nt++) {
    lp[nt] += __shfl_xor(lp[nt], 16, 64);
    lp[nt] += __shfl_xor(lp[nt], 32, 64);
  }
  __syncthreads();  // all waves done with K/V buffers before aliasing
  if (l4 == 0) {
#pragma unroll
    for (int nt = 0; nt < 4; nt++) lbuf[wave * 64 + nt * 16 + l15] = lp[nt];
  }
  floatx4* red = (floatx4*)smem;  // 3 waves x 8 x 64 = 1536 floatx4 = 24KB
#pragma unroll
  for (int phase = 0; phase < 2; phase++) {
    if (wave >= 1) {
#pragma unroll
      for (int i = 0; i < 8; i++) {
        int mq = phase * 2 + (i >> 2);
        red[(wave - 1) * 512 + i * 64 + lane] = oacc[mq][i & 3];
      }
    }
    __syncthreads();
    if (wave == 0) {
#pragma unroll
      for (int i = 0; i < 8; i++) {
        int mq = phase * 2 + (i >> 2);
        oacc[mq][i & 3] += red[i * 64 + lane] + red[512 + i * 64 + lane] +
                           red[1024 + i * 64 + lane];
      }
    }
    __syncthreads();
  }
  if (wave == 0) {
    float lt[4];
#pragma unroll
    for (int nt = 0; nt < 4; nt++)
      lt[nt] = lbuf[nt * 16 + l15] + lbuf[64 + nt * 16 + l15] +
               lbuf[128 + nt * 16 + l15] + lbuf[192 + nt * 16 + l15];
    float rl[4][4];
#pragma unroll
    for (int mq = 0; mq < 4; mq++)
#pragma unroll
      for (int r = 0; r < 4; r++)
        rl[mq][r] = 1.0f / __shfl(lt[mq], (lane & 48) | (l4 * 4 + r), 64);
#pragma unroll
    for (int mq = 0; mq < 4; mq++) {
#pragma unroll
      for (int nt = 0; nt < 4; nt++) {
#pragma unroll
        for (int r = 0; r < 4; r++) {
          float v = oacc[mq][nt][r] * rl[mq][r];
          int gs = q0 + mq * 16 + l4 * 4 + r;
          int gd = h * 64 + nt * 16 + l15;
          size_t o = ((size_t)b * 2048 + gs) * 512 + gd;
          bf16 hi, lo;
          split2(v, hi, lo);
          O_hi[o] = hi;
          O_lo[o] = lo;
        }
      }
    }
  }
}

// ---------------------------------------------------------------------------
// Output projection, 64x128 C-tile, BK=32, single-buffer (24KB) two-phase
// sync + setprio. grid 512, m-major -> 2 blocks/CU. (R19-exact)
// ---------------------------------------------------------------------------
__global__ __launch_bounds__(256, 2) void k_proj_out(
    const bf16* __restrict__ O_hi, const bf16* __restrict__ O_lo,
    const bf16* __restrict__ wt_hi, const bf16* __restrict__ wt_lo,
    float* __restrict__ out) {
  const int P = blockIdx.x;
  const int g = P & 127, n_idx = P >> 7;
  const int m0 = g * 64, n0 = n_idx * 128;

  const uint8_t* Ahb = (const uint8_t*)O_hi;
  const uint8_t* Alb = (const uint8_t*)O_lo;
  const uint8_t* Bhb = (const uint8_t*)(wt_hi + (size_t)3 * 262144);
  const uint8_t* Blb = (const uint8_t*)(wt_lo + (size_t)3 * 262144);
  const int tid = threadIdx.x, wave = tid >> 6, lane = tid & 63;
  const int l15 = lane & 15, l4 = lane >> 4;
  const int Am0 = (wave & 1) * 32, Bn0 = (wave >> 1) * 64;

  __shared__ bf16 sAh[64 * 32], sAl[64 * 32];    // 4 KB each
  __shared__ bf16 sBh[128 * 32], sBl[128 * 32];  // 8 KB each

  int aoff, adst;
  {
    int slot = tid;
    int row = slot >> 2, phys = slot & 3, lg = phys ^ (row & 3);
    aoff = (m0 + row) * 1024 + lg * 16;
    adst = slot * 16;
  }
  int boff[2], bdst[2];
#pragma unroll
  for (int p = 0; p < 2; p++) {
    int slot = p * 256 + tid;
    int row = slot >> 2, phys = slot & 3, lg = phys ^ (row & 3);
    boff[p] = (n0 + row) * 1024 + lg * 16;
    bdst[p] = slot * 16;
  }

  floatx4 acc[2][4];
#pragma unroll
  for (int i = 0; i < 2; i++)
#pragma unroll
    for (int j = 0; j < 4; j++) acc[i][j] = {0.f, 0.f, 0.f, 0.f};

  // prologue: issue stage(0)
  GLD16(Ahb + aoff, (char*)sAh + adst);
  GLD16(Alb + aoff, (char*)sAl + adst);
#pragma unroll
  for (int p = 0; p < 2; p++) {
    GLD16(Bhb + boff[p], (char*)sBh + bdst[p]);
    GLD16(Blb + boff[p], (char*)sBl + bdst[p]);
  }

  for (int kb = 0; kb < 512; kb += 32) {
    PIPE_TOP();

    bf16x8 ah[2], al[2], bhf[4], blf[4];
#pragma unroll
    for (int mt = 0; mt < 2; mt++) {
      int row = Am0 + mt * 16 + l15, r3 = row & 3;
      ah[mt] = *(const bf16x8*)((const char*)sAh + row * 64 + ((l4 ^ r3) * 16));
      al[mt] = *(const bf16x8*)((const char*)sAl + row * 64 + ((l4 ^ r3) * 16));
    }
#pragma unroll
    for (int nt = 0; nt < 4; nt++) {
      int row = Bn0 + nt * 16 + l15, r3 = row & 3;
      bhf[nt] = *(const bf16x8*)((const char*)sBh + row * 64 + ((l4 ^ r3) * 16));
      blf[nt] = *(const bf16x8*)((const char*)sBl + row * 64 + ((l4 ^ r3) * 16));
    }

    LGKM_BARRIER();

    if (kb + 32 < 512) {
      const int nkb = kb + 32;
      GLD16(Ahb + aoff + nkb * 2, (char*)sAh + adst);
      GLD16(Alb + aoff + nkb * 2, (char*)sAl + adst);
#pragma unroll
      for (int p = 0; p < 2; p++) {
        GLD16(Bhb + boff[p] + nkb * 2, (char*)sBh + bdst[p]);
        GLD16(Blb + boff[p] + nkb * 2, (char*)sBl + bdst[p]);
      }
    }

    __builtin_amdgcn_s_setprio(1);
#pragma unroll
    for (int nt = 0; nt < 4; nt++) {
#pragma unroll
      for (int mt = 0; mt < 2; mt++) {
        acc[mt][nt] = MFMA16(ah[mt], bhf[nt], acc[mt][nt]);
        acc[mt][nt] = MFMA16(ah[mt], blf[nt], acc[mt][nt]);
        acc[mt][nt] = MFMA16(al[mt], bhf[nt], acc[mt][nt]);
      }
    }
    __builtin_amdgcn_s_setprio(0);
  }
#pragma unroll
  for (int mt = 0; mt < 2; mt++) {
#pragma unroll
    for (int nt = 0; nt < 4; nt++) {
#pragma unroll
      for (int r = 0; r < 4; r++) {
        int m = m0 + Am0 + mt * 16 + l4 * 4 + r;
        int n = n0 + Bn0 + nt * 16 + l15;
        out[(size_t)m * 512 + n] = acc[mt][nt][r];
      }
    }
  }
}

// ---------------------------------------------------------------------------
extern "C" void kernel_launch(void* const* d_in, const int* in_sizes, int n_in,
                              void* d_out, int out_size, void* d_ws, size_t ws_size,
                              hipStream_t stream) {
  (void)in_sizes; (void)n_in; (void)out_size; (void)ws_size;
  const float* Xq = (const float*)d_in[0];
  const float* Xk = (const float*)d_in[1];
  const float* Xv = (const float*)d_in[2];
  const float* Wq = (const float*)d_in[3];
  const float* Wk = (const float*)d_in[4];
  const float* Wv = (const float*)d_in[5];
  const float* Wo = (const float*)d_in[6];
  float* out = (float*)d_out;

  char* ws = (char*)d_ws;
  size_t off = 0;
  auto alloc = [&](size_t n) {
    void* p = ws + off;
    off += (n + 255) & ~(size_t)255;
    return p;
  };
  const size_t NW = 4 * 262144;
  const size_t NE = 4194304;       // 4*2048*512
  const size_t NX = 3 * 4194304;   // all three X inputs
  bf16* wt_hi = (bf16*)alloc(NW * 2);
  bf16* wt_lo = (bf16*)alloc(NW * 2);
  bf16* Qh = (bf16*)alloc(NE * 2);
  bf16* Ql = (bf16*)alloc(NE * 2);
  bf16* Kk = (bf16*)alloc(NE * 2);
  bf16* Vt = (bf16*)alloc(NE * 2);
  // Xh/Xl alias Oh/Ol: Xh,Xl dead before flash writes Oh,Ol.
  char* shared_region = (char*)alloc(2 * NX * 2);
  bf16* Xh = (bf16*)shared_region;
  bf16* Xl = Xh + NX;
  bf16* Oh = (bf16*)shared_region;
  bf16* Ol = Oh + NE;

  k_split_w<<<dim3(8, 8, 4), dim3(256), 0, stream>>>(Wq, Wk, Wv, Wo, wt_hi, wt_lo);
  k_split_x<<<dim3(2048), dim3(256), 0, stream>>>(Xq, Xk, Xv, Xh, Xl);
  k_proj_qkv<<<dim3(768), dim3(256), 0, stream>>>(Xh, Xl, wt_hi, wt_lo,
                                                  Qh, Ql, Kk, Vt);
  k_flash<<<dim3(1024), dim3(256), 0, stream>>>(Qh, Ql, Kk, Vt, Oh, Ol);
  k_proj_out<<<dim3(512), dim3(256), 0, stream>>>(Oh, Ol, wt_hi, wt_lo, out);
}

// Round 13
// 220.609 us; speedup vs baseline: 1.2014x; 1.0056x over previous
//
#include <hip/hip_runtime.h>
#include <hip/hip_bf16.h>
#include <cstdint>
#include <cstddef>

// MHA: B=4, S=2048, D=512, H=8, DH=64. fp32 in/out.
// R22: T15 verdict null (R20 spill / R21 69us vs R14 63.3) -> flash main
//      loop reverted to R14-EXACT. Kept: proj_qkv/proj_out R19-exact
//      (setprio on; per-dispatch evidence), split_w/split_x. NEW: flash
//      epilogue redesigned from 2-phase wave0-serial (5 barriers, 8192
//      stores on one wave) to single-phase mq-distributed: wave w writes
//      its 12 non-own oacc slices to LDS (48KB), ONE barrier, wave w
//      reduces+normalizes+writes the mq=w output quarter. Reduction order
//      s0+((s1+s2)+s3) and lbuf order match old code -> bit-identical.

typedef __bf16 bf16;
typedef __attribute__((ext_vector_type(8))) __bf16 bf16x8;
typedef __attribute__((ext_vector_type(4))) __bf16 bf16x4;
typedef __attribute__((ext_vector_type(4))) float floatx4;

#define MFMA16(a, b, c) __builtin_amdgcn_mfma_f32_16x16x32_bf16(a, b, c, 0, 0, 0)

#define GLD16(gp, lp)                                              \
  __builtin_amdgcn_global_load_lds(                                \
      (const __attribute__((address_space(1))) unsigned int*)(gp), \
      (__attribute__((address_space(3))) unsigned int*)(lp), 16, 0, 0)

#define PIPE_TOP()                                     \
  do {                                                 \
    asm volatile("s_waitcnt vmcnt(0)" ::: "memory");   \
    __builtin_amdgcn_s_barrier();                      \
    __builtin_amdgcn_sched_barrier(0);                 \
  } while (0)

#define LGKM_BARRIER()                                 \
  do {                                                 \
    asm volatile("s_waitcnt lgkmcnt(0)" ::: "memory"); \
    __builtin_amdgcn_sched_barrier(0);                 \
    __builtin_amdgcn_s_barrier();                      \
    __builtin_amdgcn_sched_barrier(0);                 \
  } while (0)

__device__ __forceinline__ void split2(float x, bf16& hi, bf16& lo) {
  hi = (bf16)x;
  lo = (bf16)(x - (float)hi);
}

// ---------------------------------------------------------------------------
// Split + transpose the 4 weight matrices: wt[w][n][k] = W_w[k][n] as hi/lo bf16
// ---------------------------------------------------------------------------
__global__ __launch_bounds__(256) void k_split_w(
    const float* __restrict__ Wq, const float* __restrict__ Wk,
    const float* __restrict__ Wv, const float* __restrict__ Wo,
    bf16* __restrict__ wt_hi, bf16* __restrict__ wt_lo) {
  __shared__ float tile[64][65];
  const int w = blockIdx.z;
  const float* W = (w == 0) ? Wq : (w == 1) ? Wk : (w == 2) ? Wv : Wo;
  const int kb = blockIdx.y * 64, nb = blockIdx.x * 64;
  const int tid = threadIdx.x;
  const int col = tid & 63, rbase = tid >> 6;
#pragma unroll
  for (int i = 0; i < 16; i++) {
    int row = rbase + i * 4;
    tile[row][col] = W[(size_t)(kb + row) * 512 + nb + col];
  }
  __syncthreads();
#pragma unroll
  for (int i = 0; i < 16; i++) {
    int nrow = rbase + i * 4;
    float v = tile[col][nrow];
    bf16 hi, lo;
    split2(v, hi, lo);
    size_t o = (size_t)w * 262144 + (size_t)(nb + nrow) * 512 + (kb + col);
    wt_hi[o] = hi;
    wt_lo[o] = lo;
  }
}

// ---------------------------------------------------------------------------
// Pre-split X (q,k,v inputs) into bf16 hi/lo. Elementwise, memory-bound.
// ---------------------------------------------------------------------------
__global__ __launch_bounds__(256) void k_split_x(
    const float* __restrict__ Xq, const float* __restrict__ Xk,
    const float* __restrict__ Xv,
    bf16* __restrict__ Xh, bf16* __restrict__ Xl) {
  const int total = 3 * 1048576;  // float4 granules (3 x 4M floats)
  for (int j = blockIdx.x * blockDim.x + threadIdx.x; j < total;
       j += gridDim.x * blockDim.x) {
    int w = j >> 20, off = j & 1048575;
    const float* X = (w == 0) ? Xq : (w == 1) ? Xk : Xv;
    floatx4 v = *(const floatx4*)(X + (size_t)off * 4);
    bf16x4 hv, lv;
#pragma unroll
    for (int r = 0; r < 4; r++) {
      bf16 h, l;
      split2(v[r], h, l);
      hv[r] = h; lv[r] = l;
    }
    *(bf16x4*)(Xh + (size_t)w * 4194304 + (size_t)off * 4) = hv;
    *(bf16x4*)(Xl + (size_t)w * 4194304 + (size_t)off * 4) = lv;
  }
}

// ---------------------------------------------------------------------------
// QKV projection, 128x128 C-tile, BK=32, pure-bf16 operands (pre-split X).
// Single-buffer GLD16 staging (32KB) + two-phase sync + setprio on MFMA
// cluster. (256,3) -> 3 blk/CU. grid 768, block 256. (R19-exact)
// ---------------------------------------------------------------------------
__global__ __launch_bounds__(256, 3) void k_proj_qkv(
    const bf16* __restrict__ Xh, const bf16* __restrict__ Xl,
    const bf16* __restrict__ wt_hi, const bf16* __restrict__ wt_lo,
    bf16* __restrict__ Q_hi, bf16* __restrict__ Q_lo,
    bf16* __restrict__ K, bf16* __restrict__ Vt) {
  const int P = blockIdx.x;
  const int c_all = P >> 5, within = P & 31;
  const int n_idx = within >> 3, i8 = within & 7;
  const int which = c_all >> 3;
  const int g = ((c_all & 7) << 3) | i8;  // m-group 0..63
  const int m0 = g * 128, n0 = n_idx * 128;

  const uint8_t* Ahb = (const uint8_t*)(Xh + (size_t)which * 4194304);
  const uint8_t* Alb = (const uint8_t*)(Xl + (size_t)which * 4194304);
  const uint8_t* Bhb = (const uint8_t*)(wt_hi + (size_t)which * 262144);
  const uint8_t* Blb = (const uint8_t*)(wt_lo + (size_t)which * 262144);
  const int tid = threadIdx.x, wave = tid >> 6, lane = tid & 63;
  const int l15 = lane & 15, l4 = lane >> 4;
  const int Am0 = (wave & 1) * 64, Bn0 = (wave >> 1) * 64;

  __shared__ bf16 sAh[128 * 32], sAl[128 * 32];  // 8 KB each
  __shared__ bf16 sBh[128 * 32], sBl[128 * 32];  // 8 KB each

  int aoff[2], boff[2], dstp[2];
#pragma unroll
  for (int p = 0; p < 2; p++) {
    int slot = p * 256 + tid;
    int row = slot >> 2, phys = slot & 3, lg = phys ^ (row & 3);
    aoff[p] = (m0 + row) * 1024 + lg * 16;
    boff[p] = (n0 + row) * 1024 + lg * 16;
    dstp[p] = slot * 16;
  }

  floatx4 acc[4][4];
#pragma unroll
  for (int i = 0; i < 4; i++)
#pragma unroll
    for (int j = 0; j < 4; j++) acc[i][j] = {0.f, 0.f, 0.f, 0.f};

  // prologue: issue stage(0)
#pragma unroll
  for (int p = 0; p < 2; p++) {
    GLD16(Ahb + aoff[p], (char*)sAh + dstp[p]);
    GLD16(Alb + aoff[p], (char*)sAl + dstp[p]);
    GLD16(Bhb + boff[p], (char*)sBh + dstp[p]);
    GLD16(Blb + boff[p], (char*)sBl + dstp[p]);
  }

  for (int kb = 0; kb < 512; kb += 32) {
    PIPE_TOP();  // stage(kb) landed

    bf16x8 ah[4], al[4], bhf[4], blf[4];
#pragma unroll
    for (int mt = 0; mt < 4; mt++) {
      int row = Am0 + mt * 16 + l15, r3 = row & 3;
      ah[mt] = *(const bf16x8*)((const char*)sAh + row * 64 + ((l4 ^ r3) * 16));
      al[mt] = *(const bf16x8*)((const char*)sAl + row * 64 + ((l4 ^ r3) * 16));
    }
#pragma unroll
    for (int nt = 0; nt < 4; nt++) {
      int row = Bn0 + nt * 16 + l15, r3 = row & 3;
      bhf[nt] = *(const bf16x8*)((const char*)sBh + row * 64 + ((l4 ^ r3) * 16));
      blf[nt] = *(const bf16x8*)((const char*)sBl + row * 64 + ((l4 ^ r3) * 16));
    }

    LGKM_BARRIER();  // all waves consumed -> safe to overwrite

    if (kb + 32 < 512) {
      const int nkb = kb + 32;
#pragma unroll
      for (int p = 0; p < 2; p++) {
        GLD16(Ahb + aoff[p] + nkb * 2, (char*)sAh + dstp[p]);
        GLD16(Alb + aoff[p] + nkb * 2, (char*)sAl + dstp[p]);
        GLD16(Bhb + boff[p] + nkb * 2, (char*)sBh + dstp[p]);
        GLD16(Blb + boff[p] + nkb * 2, (char*)sBl + dstp[p]);
      }
    }

    __builtin_amdgcn_s_setprio(1);
#pragma unroll
    for (int nt = 0; nt < 4; nt++) {
#pragma unroll
      for (int mt = 0; mt < 4; mt++) {
        acc[mt][nt] = MFMA16(ah[mt], bhf[nt], acc[mt][nt]);
        acc[mt][nt] = MFMA16(ah[mt], blf[nt], acc[mt][nt]);
        acc[mt][nt] = MFMA16(al[mt], bhf[nt], acc[mt][nt]);
      }
    }
    __builtin_amdgcn_s_setprio(0);
  }

  const float scale = (which == 0) ? 0.125f : (which == 1) ? 1.44269504f : 1.0f;
#pragma unroll
  for (int mt = 0; mt < 4; mt++) {
#pragma unroll
    for (int nt = 0; nt < 4; nt++) {
      int m_base = m0 + Am0 + mt * 16 + l4 * 4;  // 4 consecutive rows (s)
      int n = n0 + Bn0 + nt * 16 + l15;          // h*64+d
      int h = (n >> 6) & 7, d = n & 63;
      if (which == 2) {
        // slot-permuted packed V^T store: keys 16t+4q+r -> column 8q+4t+r
        int kbase = m_base & 2047, b = m_base >> 11;
        int a32 = kbase & ~31, v = (kbase >> 2) & 7;
        int sbase = a32 + 8 * (v & 3) + 4 * (v >> 2);
        bf16x4 pv;
#pragma unroll
        for (int r = 0; r < 4; r++) pv[r] = (bf16)acc[mt][nt][r];
        *(bf16x4*)&Vt[((size_t)(b * 8 + h) * 64 + d) * 2048 + sbase] = pv;
      } else {
#pragma unroll
        for (int r = 0; r < 4; r++) {
          int m = m_base + r;
          int b = m >> 11, s = m & 2047;
          float v = acc[mt][nt][r] * scale;
          size_t o = ((size_t)(b * 8 + h) * 2048 + s) * 64 + d;
          if (which == 0) {
            bf16 hi, lo;
            split2(v, hi, lo);
            Q_hi[o] = hi; Q_lo[o] = lo;
          } else {
            K[o] = (bf16)v;  // single bf16 K
          }
        }
      }
    }
  }
}

// ---------------------------------------------------------------------------
// Flash attention: main loop R14-EXACT (dbuf 66.5KB, counted-wait, no
// setprio, no deferred PV). NEW single-phase mq-distributed epilogue:
// wave w stages its 12 non-own oacc slices in LDS (48KB), one barrier,
// then wave w sums s0+((s1+s2)+s3) (own slice from registers), normalizes
// with the same lt order, and writes the mq=w output quarter.
// ---------------------------------------------------------------------------
__global__ __launch_bounds__(256, 2) void k_flash(
    const bf16* __restrict__ Q_hi, const bf16* __restrict__ Q_lo,
    const bf16* __restrict__ K, const bf16* __restrict__ Vt,
    bf16* __restrict__ O_hi, bf16* __restrict__ O_lo) {
  const int P = blockIdx.x;
  const int hi4 = P >> 8, rem = P & 255;
  const int qt = rem >> 3;
  const int bh = hi4 * 8 + (rem & 7);
  const int b = bh >> 3, h = bh & 7;
  const int tid = threadIdx.x, wave = tid >> 6, lane = tid & 63;
  const int l15 = lane & 15, l4 = lane >> 4;
  const int q0 = qt * 64;

  // buf c: sK @ c*32768 (16KB) | sV @ c*32768+16384 (16KB); lbuf @ 65536 (1KB)
  __shared__ char smem[2 * 32768 + 1024];
  float* lbuf = (float*)(smem + 65536);

  const uint8_t* Kb = (const uint8_t*)K + (size_t)bh * 2048 * 128;
  const uint8_t* Vb = (const uint8_t*)Vt + (size_t)bh * 64 * 4096;
  int koff[4], voff[4], dst[4];
#pragma unroll
  for (int p = 0; p < 4; p++) {
    int slot = p * 256 + tid;
    {
      int row = slot >> 3, phys = slot & 7, lg = phys ^ (row & 7);
      koff[p] = row * 128 + lg * 16;
    }
    {
      int row = slot >> 4, phys = slot & 15, lg = phys ^ (row & 15);
      voff[p] = row * 4096 + lg * 16;
    }
    dst[p] = slot * 16;
  }

  // prologue: issue stage j0=0 into buf 0 (in flight under Q loads)
#pragma unroll
  for (int p = 0; p < 4; p++) {
    GLD16(Kb + koff[p], smem + dst[p]);
    GLD16(Vb + voff[p], smem + 16384 + dst[p]);
  }

  // Q fragments (B operand): lane holds Q[q=l15][dh=l4*8+j]
  bf16x8 qh[4][2], ql[4][2];
#pragma unroll
  for (int nt = 0; nt < 4; nt++) {
    const bf16* ph = Q_hi + ((size_t)bh * 2048 + q0 + nt * 16 + l15) * 64 + l4 * 8;
    const bf16* pl = Q_lo + ((size_t)bh * 2048 + q0 + nt * 16 + l15) * 64 + l4 * 8;
    qh[nt][0] = *(const bf16x8*)ph;
    qh[nt][1] = *(const bf16x8*)(ph + 32);
    ql[nt][0] = *(const bf16x8*)pl;
    ql[nt][1] = *(const bf16x8*)(pl + 32);
  }

  float lp[4] = {0.f, 0.f, 0.f, 0.f};  // l partial per q-tile (q = nt*16+l15)
  floatx4 oacc[4][4];
#pragma unroll
  for (int i = 0; i < 4; i++)
#pragma unroll
    for (int j = 0; j < 4; j++) oacc[i][j] = {0.f, 0.f, 0.f, 0.f};

  int cur = 0;
  for (int j0 = 0; j0 < 2048; j0 += 128) {
    PIPE_TOP();  // stage(j0) landed (issued last iter); all waves synced

    const char* sK = smem + cur * 32768;
    const char* sV = sK + 16384;

    // K/V fragments -> regs (8 x ds_read_b128), before next-stage issue
    bf16x8 kf[2][2];  // [ks][kt]
#pragma unroll
    for (int kt = 0; kt < 2; kt++) {
      int row = wave * 32 + kt * 16 + l15, r7 = row & 7;
#pragma unroll
      for (int ks = 0; ks < 2; ks++)
        kf[ks][kt] =
            *(const bf16x8*)(sK + row * 128 + (((ks * 4 + l4) ^ r7) * 16));
    }
    bf16x8 vf[4];
#pragma unroll
    for (int nt = 0; nt < 4; nt++) {
      int row = nt * 16 + l15;
      vf[nt] =
          *(const bf16x8*)(sV + row * 256 + (((wave * 4 + l4) ^ l15) * 16));
    }

    // issue next key-tile into the other buffer; in flight under compute
    if (j0 + 128 < 2048) {
      char* nb = smem + (cur ^ 1) * 32768;
      const size_t nj = (size_t)(j0 + 128);
#pragma unroll
      for (int p = 0; p < 4; p++) {
        GLD16(Kb + nj * 128 + koff[p], nb + dst[p]);
        GLD16(Vb + nj * 2 + voff[p], nb + 16384 + dst[p]);
      }
    }

    // S^T = K Q^T - 24: sc[kt][nt] C-tile: row=key(16), col=q (l15)
    floatx4 sc[2][4];
#pragma unroll
    for (int kt = 0; kt < 2; kt++)
#pragma unroll
      for (int nt = 0; nt < 4; nt++)
        sc[kt][nt] = {-24.f, -24.f, -24.f, -24.f};
#pragma unroll
    for (int ks = 0; ks < 2; ks++) {
#pragma unroll
      for (int nt = 0; nt < 4; nt++) {
        sc[0][nt] = MFMA16(kf[ks][0], qh[nt][ks], sc[0][nt]);
        sc[0][nt] = MFMA16(kf[ks][0], ql[nt][ks], sc[0][nt]);
        sc[1][nt] = MFMA16(kf[ks][1], qh[nt][ks], sc[1][nt]);
        sc[1][nt] = MFMA16(kf[ks][1], ql[nt][ks], sc[1][nt]);
      }
    }

    // p = exp2(s); pf[nt] directly the PV A-operand (slot = quad*8 + 4*kt + r)
    bf16x8 pf[4];
#pragma unroll
    for (int nt = 0; nt < 4; nt++) {
#pragma unroll
      for (int r = 0; r < 4; r++) {
        float p0 = __builtin_amdgcn_exp2f(sc[0][nt][r]);
        float p1 = __builtin_amdgcn_exp2f(sc[1][nt][r]);
        lp[nt] += p0 + p1;
        pf[nt][r] = (bf16)p0;
        pf[nt][4 + r] = (bf16)p1;
      }
    }

    // O += P V over this wave's 32 slots
#pragma unroll
    for (int nt = 0; nt < 4; nt++) {
#pragma unroll
      for (int mq = 0; mq < 4; mq++)
        oacc[mq][nt] = MFMA16(pf[mq], vf[nt], oacc[mq][nt]);
    }
    cur ^= 1;
  }

  // ---- epilogue: single-phase mq-distributed reduction + write ----
#pragma unroll
  for (int nt = 0; nt < 4; nt++) {
    lp[nt] += __shfl_xor(lp[nt], 16, 64);
    lp[nt] += __shfl_xor(lp[nt], 32, 64);
  }
  __syncthreads();  // all waves done with K/V buffers before aliasing red

  if (l4 == 0) {
#pragma unroll
    for (int nt = 0; nt < 4; nt++) lbuf[wave * 64 + nt * 16 + l15] = lp[nt];
  }
  // red slice (src, mq, nt): base floatx4 index (src*16 + mq*4 + nt)*64 + lane
  floatx4* red = (floatx4*)smem;  // 64KB max; only 12 slices/wave written
#pragma unroll
  for (int mq = 0; mq < 4; mq++) {
    if (mq != wave) {
#pragma unroll
      for (int nt = 0; nt < 4; nt++)
        red[(wave * 16 + mq * 4 + nt) * 64 + lane] = oacc[mq][nt];
    }
  }
  __syncthreads();

  {
    const int mq = wave;  // this wave finalizes q rows q0 + mq*16 .. +16
    // sum in old order: s0 + ((s1 + s2) + s3)
    floatx4 fin[4];
#pragma unroll
    for (int nt = 0; nt < 4; nt++) {
      floatx4 s0 = (wave == 0) ? oacc[mq][nt]
                               : red[(0 * 16 + mq * 4 + nt) * 64 + lane];
      floatx4 s1 = (wave == 1) ? oacc[mq][nt]
                               : red[(1 * 16 + mq * 4 + nt) * 64 + lane];
      floatx4 s2 = (wave == 2) ? oacc[mq][nt]
                               : red[(2 * 16 + mq * 4 + nt) * 64 + lane];
      floatx4 s3 = (wave == 3) ? oacc[mq][nt]
                               : red[(3 * 16 + mq * 4 + nt) * 64 + lane];
      fin[nt] = s0 + ((s1 + s2) + s3);
    }
    // lt for this mq, same summation order as before
    float ltw = lbuf[mq * 16 + l15] + lbuf[64 + mq * 16 + l15] +
                lbuf[128 + mq * 16 + l15] + lbuf[192 + mq * 16 + l15];
    float rlw[4];
#pragma unroll
    for (int r = 0; r < 4; r++)
      rlw[r] = 1.0f / __shfl(ltw, (lane & 48) | (l4 * 4 + r), 64);
#pragma unroll
    for (int nt = 0; nt < 4; nt++) {
#pragma unroll
      for (int r = 0; r < 4; r++) {
        float v = fin[nt][r] * rlw[r];
        int gs = q0 + mq * 16 + l4 * 4 + r;
        int gd = h * 64 + nt * 16 + l15;
        size_t o = ((size_t)b * 2048 + gs) * 512 + gd;
        bf16 hi, lo;
        split2(v, hi, lo);
        O_hi[o] = hi;
        O_lo[o] = lo;
      }
    }
  }
}

// ---------------------------------------------------------------------------
// Output projection, 64x128 C-tile, BK=32, single-buffer (24KB) two-phase
// sync + setprio. grid 512, m-major -> 2 blocks/CU. (R19-exact)
// ---------------------------------------------------------------------------
__global__ __launch_bounds__(256, 2) void k_proj_out(
    const bf16* __restrict__ O_hi, const bf16* __restrict__ O_lo,
    const bf16* __restrict__ wt_hi, const bf16* __restrict__ wt_lo,
    float* __restrict__ out) {
  const int P = blockIdx.x;
  const int g = P & 127, n_idx = P >> 7;
  const int m0 = g * 64, n0 = n_idx * 128;

  const uint8_t* Ahb = (const uint8_t*)O_hi;
  const uint8_t* Alb = (const uint8_t*)O_lo;
  const uint8_t* Bhb = (const uint8_t*)(wt_hi + (size_t)3 * 262144);
  const uint8_t* Blb = (const uint8_t*)(wt_lo + (size_t)3 * 262144);
  const int tid = threadIdx.x, wave = tid >> 6, lane = tid & 63;
  const int l15 = lane & 15, l4 = lane >> 4;
  const int Am0 = (wave & 1) * 32, Bn0 = (wave >> 1) * 64;

  __shared__ bf16 sAh[64 * 32], sAl[64 * 32];    // 4 KB each
  __shared__ bf16 sBh[128 * 32], sBl[128 * 32];  // 8 KB each

  int aoff, adst;
  {
    int slot = tid;
    int row = slot >> 2, phys = slot & 3, lg = phys ^ (row & 3);
    aoff = (m0 + row) * 1024 + lg * 16;
    adst = slot * 16;
  }
  int boff[2], bdst[2];
#pragma unroll
  for (int p = 0; p < 2; p++) {
    int slot = p * 256 + tid;
    int row = slot >> 2, phys = slot & 3, lg = phys ^ (row & 3);
    boff[p] = (n0 + row) * 1024 + lg * 16;
    bdst[p] = slot * 16;
  }

  floatx4 acc[2][4];
#pragma unroll
  for (int i = 0; i < 2; i++)
#pragma unroll
    for (int j = 0; j < 4; j++) acc[i][j] = {0.f, 0.f, 0.f, 0.f};

  // prologue: issue stage(0)
  GLD16(Ahb + aoff, (char*)sAh + adst);
  GLD16(Alb + aoff, (char*)sAl + adst);
#pragma unroll
  for (int p = 0; p < 2; p++) {
    GLD16(Bhb + boff[p], (char*)sBh + bdst[p]);
    GLD16(Blb + boff[p], (char*)sBl + bdst[p]);
  }

  for (int kb = 0; kb < 512; kb += 32) {
    PIPE_TOP();

    bf16x8 ah[2], al[2], bhf[4], blf[4];
#pragma unroll
    for (int mt = 0; mt < 2; mt++) {
      int row = Am0 + mt * 16 + l15, r3 = row & 3;
      ah[mt] = *(const bf16x8*)((const char*)sAh + row * 64 + ((l4 ^ r3) * 16));
      al[mt] = *(const bf16x8*)((const char*)sAl + row * 64 + ((l4 ^ r3) * 16));
    }
#pragma unroll
    for (int nt = 0; nt < 4; nt++) {
      int row = Bn0 + nt * 16 + l15, r3 = row & 3;
      bhf[nt] = *(const bf16x8*)((const char*)sBh + row * 64 + ((l4 ^ r3) * 16));
      blf[nt] = *(const bf16x8*)((const char*)sBl + row * 64 + ((l4 ^ r3) * 16));
    }

    LGKM_BARRIER();

    if (kb + 32 < 512) {
      const int nkb = kb + 32;
      GLD16(Ahb + aoff + nkb * 2, (char*)sAh + adst);
      GLD16(Alb + aoff + nkb * 2, (char*)sAl + adst);
#pragma unroll
      for (int p = 0; p < 2; p++) {
        GLD16(Bhb + boff[p] + nkb * 2, (char*)sBh + bdst[p]);
        GLD16(Blb + boff[p] + nkb * 2, (char*)sBl + bdst[p]);
      }
    }

    __builtin_amdgcn_s_setprio(1);
#pragma unroll
    for (int nt = 0; nt < 4; nt++) {
#pragma unroll
      for (int mt = 0; mt < 2; mt++) {
        acc[mt][nt] = MFMA16(ah[mt], bhf[nt], acc[mt][nt]);
        acc[mt][nt] = MFMA16(ah[mt], blf[nt], acc[mt][nt]);
        acc[mt][nt] = MFMA16(al[mt], bhf[nt], acc[mt][nt]);
      }
    }
    __builtin_amdgcn_s_setprio(0);
  }
#pragma unroll
  for (int mt = 0; mt < 2; mt++) {
#pragma unroll
    for (int nt = 0; nt < 4; nt++) {
#pragma unroll
      for (int r = 0; r < 4; r++) {
        int m = m0 + Am0 + mt * 16 + l4 * 4 + r;
        int n = n0 + Bn0 + nt * 16 + l15;
        out[(size_t)m * 512 + n] = acc[mt][nt][r];
      }
    }
  }
}

// ---------------------------------------------------------------------------
extern "C" void kernel_launch(void* const* d_in, const int* in_sizes, int n_in,
                              void* d_out, int out_size, void* d_ws, size_t ws_size,
                              hipStream_t stream) {
  (void)in_sizes; (void)n_in; (void)out_size; (void)ws_size;
  const float* Xq = (const float*)d_in[0];
  const float* Xk = (const float*)d_in[1];
  const float* Xv = (const float*)d_in[2];
  const float* Wq = (const float*)d_in[3];
  const float* Wk = (const float*)d_in[4];
  const float* Wv = (const float*)d_in[5];
  const float* Wo = (const float*)d_in[6];
  float* out = (float*)d_out;

  char* ws = (char*)d_ws;
  size_t off = 0;
  auto alloc = [&](size_t n) {
    void* p = ws + off;
    off += (n + 255) & ~(size_t)255;
    return p;
  };
  const size_t NW = 4 * 262144;
  const size_t NE = 4194304;       // 4*2048*512
  const size_t NX = 3 * 4194304;   // all three X inputs
  bf16* wt_hi = (bf16*)alloc(NW * 2);
  bf16* wt_lo = (bf16*)alloc(NW * 2);
  bf16* Qh = (bf16*)alloc(NE * 2);
  bf16* Ql = (bf16*)alloc(NE * 2);
  bf16* Kk = (bf16*)alloc(NE * 2);
  bf16* Vt = (bf16*)alloc(NE * 2);
  // Xh/Xl alias Oh/Ol: Xh,Xl dead before flash writes Oh,Ol.
  char* shared_region = (char*)alloc(2 * NX * 2);
  bf16* Xh = (bf16*)shared_region;
  bf16* Xl = Xh + NX;
  bf16* Oh = (bf16*)shared_region;
  bf16* Ol = Oh + NE;

  k_split_w<<<dim3(8, 8, 4), dim3(256), 0, stream>>>(Wq, Wk, Wv, Wo, wt_hi, wt_lo);
  k_split_x<<<dim3(2048), dim3(256), 0, stream>>>(Xq, Xk, Xv, Xh, Xl);
  k_proj_qkv<<<dim3(768), dim3(256), 0, stream>>>(Xh, Xl, wt_hi, wt_lo,
                                                  Qh, Ql, Kk, Vt);
  k_flash<<<dim3(1024), dim3(256), 0, stream>>>(Qh, Ql, Kk, Vt, Oh, Ol);
  k_proj_out<<<dim3(512), dim3(256), 0, stream>>>(Oh, Ol, wt_hi, wt_lo, out);
}